// Round 10
// baseline (330.978 us; speedup 1.0000x reference)
//
#include <hip/hip_runtime.h>
#include <hip/hip_fp16.h>
#include <stdint.h>

typedef unsigned short u16;
typedef unsigned int u32;
typedef long i64;
typedef short bf16x8 __attribute__((ext_vector_type(8)));
typedef float f32x4 __attribute__((ext_vector_type(4)));

#define SCALE_C   1024.f
#define INV_SCALE 0.0009765625f

__device__ __forceinline__ float bf2f(u16 v) { return __uint_as_float(((u32)v) << 16); }

__device__ __forceinline__ u16 f2bf(float a) {
  u32 u = __float_as_uint(a); u += 0x7FFFu + ((u >> 16) & 1u); return (u16)(u >> 16);
}

__device__ __forceinline__ u32 packbf2(float a, float b) {
  u32 ua = __float_as_uint(a); ua += 0x7FFFu + ((ua >> 16) & 1u);
  u32 ub = __float_as_uint(b); ub += 0x7FFFu + ((ub >> 16) & 1u);
  return (ua >> 16) | (ub & 0xFFFF0000u);
}

// 4 floats -> 4 fp8 e4m3 in one dword (2x v_cvt_pk_fp8_f32)
__device__ __forceinline__ u32 packfp8x4(float a, float b, float c, float d) {
  u32 lo = (u32)__builtin_amdgcn_cvt_pk_fp8_f32(a, b, 0, false);
  return (u32)__builtin_amdgcn_cvt_pk_fp8_f32(c, d, (int)lo, true);
}

__device__ __forceinline__ float inval(const void* p, int idx, int isf) {
  return isf ? ((const float*)p)[idx] : bf2f(((const u16*)p)[idx]);
}

// async global->LDS, 16 B per lane, zero VGPR cost. LDS dest must be
// wave-uniform base (HW writes base + lane*16); global src is per-lane.
__device__ __forceinline__ void async_cp16(const void* g, void* l) {
  __builtin_amdgcn_global_load_lds(
      (const __attribute__((address_space(1))) void*)g,
      (__attribute__((address_space(3))) void*)l, 16, 0, 0);
}

// 16-term Chebyshev cos/sin basis -> 8 packed fp8 dwords (x1024 scale in W).
__device__ __forceinline__ void basis16(float a, u32* pk) {
  float s1, c1; __sincosf(a, &s1, &c1);
  float t2 = c1 + c1;
  float cg[16], sg[16];
  cg[0] = c1; sg[0] = s1;
  cg[1] = fmaf(t2, c1, -1.f); sg[1] = t2 * s1;
  #pragma unroll
  for (int g = 2; g < 16; ++g) {
    cg[g] = fmaf(t2, cg[g-1], -cg[g-2]);
    sg[g] = fmaf(t2, sg[g-1], -sg[g-2]);
  }
  #pragma unroll
  for (int j = 0; j < 4; ++j) pk[j]   = packfp8x4(cg[4*j], cg[4*j+1], cg[4*j+2], cg[4*j+3]);
  #pragma unroll
  for (int j = 0; j < 4; ++j) pk[4+j] = packfp8x4(sg[4*j], sg[4*j+1], sg[4*j+2], sg[4*j+3]);
}

// 8-term basis -> 4 packed fp8 dwords (cos x2, sin x2).
__device__ __forceinline__ void basis8(float a, u32* pk) {
  float s1, c1; __sincosf(a, &s1, &c1);
  float t2 = c1 + c1;
  float cg[8], sg[8];
  cg[0] = c1; sg[0] = s1;
  cg[1] = fmaf(t2, c1, -1.f); sg[1] = t2 * s1;
  #pragma unroll
  for (int g = 2; g < 8; ++g) {
    cg[g] = fmaf(t2, cg[g-1], -cg[g-2]);
    sg[g] = fmaf(t2, sg[g-1], -sg[g-2]);
  }
  pk[0] = packfp8x4(cg[0], cg[1], cg[2], cg[3]);
  pk[1] = packfp8x4(cg[4], cg[5], cg[6], cg[7]);
  pk[2] = packfp8x4(sg[0], sg[1], sg[2], sg[3]);
  pk[3] = packfp8x4(sg[4], sg[5], sg[6], sg[7]);
}

// Q3 partial-plane byte offsets within workspace: regions dead by kan3-time
// (H 0-16M, W2F8 16-24M, Xs 26-33M, W1s 33-34M). W3F8 (24-26M) and P2
// (34-66M) are live during kan3 and are avoided.
#define QOF(k) ((size_t)((k) < 6 ? (k) * 4 : 26 + ((k) - 6) * 4) << 20)

// ---------------------------------------------------------------------------
// prep_all: detect dtype + split(x,W1) to bf16-split + coeffs -> fp8 (x1024)
// + zero the 64 slab counters for kan3's fused-softmax tail.
// ---------------------------------------------------------------------------
__device__ __forceinline__ void split_body(
    const void* __restrict__ src, u16* __restrict__ dst, int i, int isf, int lo_pos)
{
  int row = i >> 6, g = i & 63;
  float v[4];
  if (isf) {
    float4 t = ((const float4*)src)[i];
    v[0] = t.x; v[1] = t.y; v[2] = t.z; v[3] = t.w;
  } else {
    uint2 t = ((const uint2*)src)[i];
    const u16* p = (const u16*)&t;
    v[0] = bf2f(p[0]); v[1] = bf2f(p[1]); v[2] = bf2f(p[2]); v[3] = bf2f(p[3]);
  }
  u16 hi[4]; float lo[4];
  #pragma unroll
  for (int j = 0; j < 4; ++j) { hi[j] = f2bf(v[j]); lo[j] = v[j] - bf2f(hi[j]); }
  u32 hw0 = (u32)hi[0] | ((u32)hi[1] << 16);
  u32 hw1 = (u32)hi[2] | ((u32)hi[3] << 16);
  u32 lw0 = packbf2(lo[0], lo[1]);
  u32 lw1 = packbf2(lo[2], lo[3]);
  u32* base = (u32*)(dst + (size_t)row * 768);
  int c = g * 2;
  base[c] = hw0; base[c + 1] = hw1;
  if (lo_pos == 1) {
    base[128 + c] = lw0; base[128 + c + 1] = lw1;
    base[256 + c] = hw0; base[256 + c + 1] = hw1;
  } else {
    base[128 + c] = hw0; base[128 + c + 1] = hw1;
    base[256 + c] = lw0; base[256 + c + 1] = lw1;
  }
}

__global__ __launch_bounds__(256) void prep_all_kernel(
    const void* __restrict__ x, const void* __restrict__ W1,
    u16* __restrict__ Xs, u16* __restrict__ W1s,
    const void* __restrict__ c2, unsigned char* __restrict__ w2f8,
    const void* __restrict__ c3, unsigned char* __restrict__ w3f8,
    int* __restrict__ flag, int* __restrict__ cnt)
{
  __shared__ int sf[4];
  const int t = threadIdx.x, wave = t >> 6;
  {
    float v = fabsf(bf2f(((const u16*)W1)[t & 127]));
    int bad = !(v < 1e6f);
    unsigned long long b = __ballot(bad);
    if ((t & 63) == 0) sf[wave] = (b != 0ull) ? 1 : 0;
  }
  __syncthreads();
  const int isf = sf[0] | sf[1] | sf[2] | sf[3];
  const int bid = blockIdx.x;
  if (bid == 0 && t == 0) *flag = isf;
  if (bid == 1 && t < 64) cnt[t] = 0;      // zero kan3 slab counters
  if (bid < 1024) {
    split_body(x, Xs, bid * 256 + t, isf, 1);
  } else if (bid < 1152) {
    split_body(W1, W1s, (bid - 1024) * 256 + t, isf, 2);
  } else if (bid < 2176) {
    int u = (bid - 1152) * 256 + t;           // 512*512 (o,i)
    int o = u >> 9, i = u & 511;
    u32* d = (u32*)(w2f8 + (size_t)o * 16384 + i * 32);
    if (isf) {
      const float4* f0 = (const float4*)((const float*)c2 + ((size_t)o * 512 + i) * 16);
      const float4* f1 = (const float4*)((const float*)c2 + (size_t)512 * 512 * 16 + ((size_t)o * 512 + i) * 16);
      #pragma unroll
      for (int j = 0; j < 4; ++j) { float4 v = f0[j]; d[j]   = packfp8x4(v.x*SCALE_C, v.y*SCALE_C, v.z*SCALE_C, v.w*SCALE_C); }
      #pragma unroll
      for (int j = 0; j < 4; ++j) { float4 v = f1[j]; d[4+j] = packfp8x4(v.x*SCALE_C, v.y*SCALE_C, v.z*SCALE_C, v.w*SCALE_C); }
    } else {
      const u16* s0 = (const u16*)c2 + ((size_t)o * 512 + i) * 16;
      const u16* s1 = (const u16*)c2 + (size_t)512 * 512 * 16 + ((size_t)o * 512 + i) * 16;
      #pragma unroll
      for (int j = 0; j < 4; ++j) d[j]   = packfp8x4(bf2f(s0[4*j])*SCALE_C, bf2f(s0[4*j+1])*SCALE_C, bf2f(s0[4*j+2])*SCALE_C, bf2f(s0[4*j+3])*SCALE_C);
      #pragma unroll
      for (int j = 0; j < 4; ++j) d[4+j] = packfp8x4(bf2f(s1[4*j])*SCALE_C, bf2f(s1[4*j+1])*SCALE_C, bf2f(s1[4*j+2])*SCALE_C, bf2f(s1[4*j+3])*SCALE_C);
    }
  } else {
    int u = (bid - 2176) * 256 + t;           // 256*512 (o,i)
    int o = u >> 9, i = u & 511;
    u32* d = (u32*)(w3f8 + (size_t)o * 8192 + i * 16);
    if (isf) {
      const float4* f0 = (const float4*)((const float*)c3 + ((size_t)o * 512 + i) * 8);
      const float4* f1 = (const float4*)((const float*)c3 + (size_t)256 * 512 * 8 + ((size_t)o * 512 + i) * 8);
      #pragma unroll
      for (int j = 0; j < 2; ++j) { float4 v = f0[j]; d[j]   = packfp8x4(v.x*SCALE_C, v.y*SCALE_C, v.z*SCALE_C, v.w*SCALE_C); }
      #pragma unroll
      for (int j = 0; j < 2; ++j) { float4 v = f1[j]; d[2+j] = packfp8x4(v.x*SCALE_C, v.y*SCALE_C, v.z*SCALE_C, v.w*SCALE_C); }
    } else {
      const u16* s0 = (const u16*)c3 + ((size_t)o * 512 + i) * 8;
      const u16* s1 = (const u16*)c3 + (size_t)256 * 512 * 8 + ((size_t)o * 512 + i) * 8;
      #pragma unroll
      for (int j = 0; j < 2; ++j) d[j]   = packfp8x4(bf2f(s0[4*j])*SCALE_C, bf2f(s0[4*j+1])*SCALE_C, bf2f(s0[4*j+2])*SCALE_C, bf2f(s0[4*j+3])*SCALE_C);
      #pragma unroll
      for (int j = 0; j < 2; ++j) d[2+j] = packfp8x4(bf2f(s1[4*j])*SCALE_C, bf2f(s1[4*j+1])*SCALE_C, bf2f(s1[4*j+2])*SCALE_C, bf2f(s1[4*j+3])*SCALE_C);
    }
  }
}

// ---------------------------------------------------------------------------
// Kernel 1: h = x @ W1^T + b1 via split-bf16 (K=768), fp32 out + sum/sumsq.
// 64-row n-tiles, grid (64,8)=512 blocks -> 2 blocks/CU. (r4 form)
// ---------------------------------------------------------------------------
#define L1_LD 136
__global__ __launch_bounds__(256) void l1_kernel(
    const u16* __restrict__ xs, const u16* __restrict__ w1s, const void* __restrict__ b1,
    const int* __restrict__ flag, float* __restrict__ H, float2* __restrict__ PT)
{
  __shared__ u16 sA[64 * L1_LD];
  __shared__ u16 sB[64 * L1_LD];
  __shared__ float redbuf[8];
  const int n0 = blockIdx.x * 64, o0 = blockIdx.y * 64;
  const int t = threadIdx.x, wave = t >> 6, lane = t & 63, quad = lane >> 4, l16 = lane & 15;
  const int isf = *flag;
  f32x4 acc[4] = {};
  for (int ks = 0; ks < 768; ks += 128) {
    #pragma unroll
    for (int r = 0; r < 4; ++r) {
      int idx = t + r * 256, row = idx >> 4, col = idx & 15;
      *(uint4*)&sA[row * L1_LD + col * 8] =
          *((const uint4*)(xs + (size_t)(n0 + row) * 768 + ks) + col);
    }
    #pragma unroll
    for (int r = 0; r < 4; ++r) {
      int idx = t + r * 256, row = idx >> 4, col = idx & 15;
      *(uint4*)&sB[row * L1_LD + col * 8] =
          *((const uint4*)(w1s + (size_t)(o0 + row) * 768 + ks) + col);
    }
    __syncthreads();
    #pragma unroll
    for (int kk = 0; kk < 128; kk += 32) {
      bf16x8 av = *(const bf16x8*)&sA[(wave * 16 + l16) * L1_LD + kk + quad * 8];
      #pragma unroll
      for (int fo = 0; fo < 4; ++fo) {
        bf16x8 bv = *(const bf16x8*)&sB[(fo * 16 + l16) * L1_LD + kk + quad * 8];
        acc[fo] = __builtin_amdgcn_mfma_f32_16x16x32_bf16(av, bv, acc[fo], 0, 0, 0);
      }
    }
    __syncthreads();
  }
  float s = 0.f, sq = 0.f;
  #pragma unroll
  for (int fo = 0; fo < 4; ++fo) {
    int o = o0 + fo * 16 + l16;
    float bias = inval(b1, o, isf);
    #pragma unroll
    for (int r = 0; r < 4; ++r) {
      int n = n0 + wave * 16 + quad * 4 + r;
      float h = acc[fo][r] + bias;
      H[(size_t)n * 512 + o] = h;
      s += h; sq += h * h;
    }
  }
  #pragma unroll
  for (int off = 32; off; off >>= 1) { s += __shfl_down(s, off); sq += __shfl_down(sq, off); }
  if (lane == 0) { redbuf[wave] = s; redbuf[4 + wave] = sq; }
  __syncthreads();
  if (t == 0) {
    float S = redbuf[0] + redbuf[1] + redbuf[2] + redbuf[3];
    float Q = redbuf[4] + redbuf[5] + redbuf[6] + redbuf[7];
    PT[blockIdx.y * 64 + blockIdx.x] = make_float2(S, Q);
  }
}

// ---------------------------------------------------------------------------
// Kernel 3: BN+ReLU+basis + FP8 MFMA GEMM — producer/consumer wave split
// (r4/r7 form, best measured 60.9us). Plane-partial P2 output (kz=4).
// ---------------------------------------------------------------------------
#define K2_LDB 128
__global__ __launch_bounds__(512, 4) void kan2_kernel(
    const float* __restrict__ H, const unsigned char* __restrict__ w2f8,
    const void* __restrict__ gammap, const void* __restrict__ betap,
    const int* __restrict__ flag, const float2* __restrict__ PT,
    float* __restrict__ P, int kzT)
{
  __shared__ __attribute__((aligned(16))) unsigned char smem[81920];
  // layout: A0[0,8K) A1[8K,16K) B0[16K,48K) B1[48K,80K); sred in B1 tail
  float* sred = (float*)(smem + 81888);
  const int n0 = blockIdx.x * 64, o0 = blockIdx.y * 256, kz = blockIdx.z;
  const int t = threadIdx.x, wave = t >> 6, lane = t & 63, quad = lane >> 4, l16 = lane & 15;
  const int nst = 128 / kzT;               // 32 for kzT=4
  const int i0 = kz * nst * 4;
  const int csw = (l16 & 7) << 4;
  const int isf = *flag;

  // producer-side state
  const int pt = t - 256;
  const int am = pt >> 2, ai = pt & 3;     // 64 rows x 4 i
  const int r0 = pt >> 3, seg = pt & 7;    // B staging map
  const unsigned char* bsrc = w2f8 + (size_t)(o0 + (r0 & 63)) * 16384 + (size_t)i0 * 32
                              + (((seg & 7) * 16) ^ ((r0 & 7) << 4));
  const float* hsrc = H + (size_t)(n0 + (am & 63)) * 512 + i0 + (ai & 3);
  const int acol0 = ((ai & 3) * 32) ^ ((am & 7) << 4);
  const int acol1 = ((ai & 3) * 32 + 16) ^ ((am & 7) << 4);
  float mean = 0.f, gs = 0.f, beta = 0.f, ph = 0.f;
  u32 pk[8];

  if (wave >= 4) {
    // issue B(0) async into B0 (drains at barrier 1)
    unsigned char* b0 = smem + 16384 + (wave - 4) * 1024;
    #pragma unroll
    for (int p = 0; p < 8; ++p)
      async_cp16(bsrc + (size_t)p * 32 * 16384, b0 + p * 4096);
    // stats partial reduce
    float2 pa = PT[pt], pb = PT[pt + 256];
    float ss = pa.x + pb.x, qs = pa.y + pb.y;
    #pragma unroll
    for (int off = 32; off; off >>= 1) { ss += __shfl_down(ss, off); qs += __shfl_down(qs, off); }
    if (lane == 0) { sred[(wave - 4) * 2] = ss; sred[(wave - 4) * 2 + 1] = qs; }
  }
  __syncthreads();                         // sred visible; B(0) drained
  if (wave >= 4) {
    const float Ssum = sred[0] + sred[2] + sred[4] + sred[6];
    const float Qsum = sred[1] + sred[3] + sred[5] + sred[7];
    const float Nn = 4096.f * 512.f;
    mean = Ssum / Nn;
    const float rstd = rsqrtf(Qsum / Nn - mean * mean + 1e-5f);
    gs = inval(gammap, 0, isf) * rstd;
    beta = inval(betap, 0, isf);
    // A(0): trig for step 0
    float a = fmaxf((*hsrc - mean) * gs + beta, 0.f);
    hsrc += 4;
    basis16(a, pk);
    *(uint4*)&smem[am * K2_LDB + acol0] = *(uint4*)&pk[0];
    *(uint4*)&smem[am * K2_LDB + acol1] = *(uint4*)&pk[4];
    if (nst > 1) { ph = *hsrc; hsrc += 4; }
  }
  __syncthreads();                         // A(0) visible

  f32x4 acc[2][8] = {};
  const int wm = (wave & 1) * 32, wo = (wave >> 1) * 128;  // consumer tile
  int cur = 0;
  for (int s = 0; s < nst; ++s) {
    const int nxt = cur ^ 1;
    if (wave >= 4) {
      if (s + 1 < nst) {
        bsrc += 128;
        unsigned char* bn = smem + 16384 + nxt * 32768 + (wave - 4) * 1024;
        #pragma unroll
        for (int p = 0; p < 8; ++p)
          async_cp16(bsrc + (size_t)p * 32 * 16384, bn + p * 4096);
        float a = fmaxf((ph - mean) * gs + beta, 0.f);
        basis16(a, pk);
        unsigned char* an = smem + nxt * 8192;
        *(uint4*)&an[am * K2_LDB + acol0] = *(uint4*)&pk[0];
        *(uint4*)&an[am * K2_LDB + acol1] = *(uint4*)&pk[4];
        if (s + 2 < nst) { ph = *hsrc; hsrc += 4; }
      }
    } else {
      const unsigned char* ac = smem + cur * 8192;
      const unsigned char* bc = smem + 16384 + cur * 32768;
      #pragma unroll
      for (int kk = 0; kk < 128; kk += 32) {
        const int cb = (kk + quad * 8) ^ csw;
        i64 bfr[8], afr[2];
        #pragma unroll
        for (int fo = 0; fo < 8; ++fo)
          bfr[fo] = *(const i64*)&bc[(wo + fo * 16 + l16) * K2_LDB + cb];
        #pragma unroll
        for (int fm = 0; fm < 2; ++fm)
          afr[fm] = *(const i64*)&ac[(wm + fm * 16 + l16) * K2_LDB + cb];
        #pragma unroll
        for (int fm = 0; fm < 2; ++fm)
        #pragma unroll
        for (int fo = 0; fo < 8; ++fo)
          acc[fm][fo] = __builtin_amdgcn_mfma_f32_16x16x32_fp8_fp8(afr[fm], bfr[fo], acc[fm][fo], 0, 0, 0);
      }
    }
    __syncthreads();                       // drains B(s+1) async + A(s+1) writes
    cur = nxt;
  }
  if (wave < 4) {
    float* Pk = P + (size_t)kz * (4096 * 512);
    #pragma unroll
    for (int fm = 0; fm < 2; ++fm)
    #pragma unroll
    for (int fo = 0; fo < 8; ++fo) {
      int o = o0 + wo + fo * 16 + l16;
      #pragma unroll
      for (int r = 0; r < 4; ++r) {
        int n = n0 + wm + fm * 16 + quad * 4 + r;
        Pk[(size_t)n * 512 + o] = acc[fm][fo][r] * INV_SCALE;
      }
    }
  }
}

// ---------------------------------------------------------------------------
// Kernel 4: basis + FP8 MFMA GEMM — producer/consumer wave split (r7 form)
// + FUSED last-block reduce + softmax tail. The 8 kz-blocks of each n-slab
// write partial planes (plain stores), fence, and bump cnt[slab]; the 8th
// block acquires, reduces 8 planes + bias3, and writes softmax to d_out.
// Removes the separate softmax kernel (one fewer serial pipeline stage).
// ---------------------------------------------------------------------------
#define K3_LDB 128
__global__ __launch_bounds__(512, 4) void kan3_kernel(
    const float* __restrict__ P2, const void* __restrict__ bias2,
    const unsigned char* __restrict__ w3f8,
    const int* __restrict__ flag, char* __restrict__ wsbase, int kzT2,
    const void* __restrict__ bias3, float* __restrict__ out,
    int* __restrict__ cnt)
{
  // layout: A0[0,8K) A1[8K,16K) B0[16K,48K) B1[48K,80K)
  __shared__ __attribute__((aligned(16))) unsigned char smem[81920];
  const int n0 = blockIdx.x * 64, kz = blockIdx.z;
  const int t = threadIdx.x, wave = t >> 6, lane = t & 63, quad = lane >> 4, l16 = lane & 15;
  const int i0 = kz * 64;                  // 64 i per block, 8 steps x 8 i
  const int nst = 8;
  const int csw = (l16 & 7) << 4;
  const int isf = *flag;

  // producer-side state
  const int pt = t - 256;
  const int am = (pt >> 2) & 63;           // producer n-row 0..63
  const int il = (pt & 3) * 2;             // i-pair base within step
  const int r0 = (pt >> 3) & 31, seg = pt & 7;
  const unsigned char* bsrc = w3f8 + (size_t)r0 * 8192 + (size_t)i0 * 16
                              + ((seg * 16) ^ ((r0 & 7) << 4));
  const float* psrc = P2 + (size_t)(n0 + am) * 512 + i0 + il;
  const int acol0 = (il * 16) ^ ((am & 7) << 4);
  const int acol1 = ((il + 1) * 16) ^ ((am & 7) << 4);
  float2 ph2 = make_float2(0.f, 0.f);
  u32 pkA[4], pkB[4];

  if (wave >= 4) {
    // B(0) async into B0
    unsigned char* b0 = smem + 16384 + (wave - 4) * 1024;
    #pragma unroll
    for (int p = 0; p < 8; ++p)
      async_cp16(bsrc + (size_t)p * 32 * 8192, b0 + p * 4096);
    // ph for step 0: bias2 + sum of kzT2 P2 planes
    float v0 = inval(bias2, i0 + il, isf);
    float v1 = inval(bias2, i0 + il + 1, isf);
    for (int k = 0; k < kzT2; ++k) {
      float2 pp = *(const float2*)(psrc + (size_t)k * 4096 * 512);
      v0 += pp.x; v1 += pp.y;
    }
    basis8(v0, pkA); basis8(v1, pkB);
    *(uint4*)&smem[am * K3_LDB + acol0] = *(uint4*)&pkA[0];
    *(uint4*)&smem[am * K3_LDB + acol1] = *(uint4*)&pkB[0];
    // prefetch ph for step 1
    psrc += 8;
    float w0 = inval(bias2, i0 + 8 + il, isf);
    float w1 = inval(bias2, i0 + 8 + il + 1, isf);
    for (int k = 0; k < kzT2; ++k) {
      float2 pp = *(const float2*)(psrc + (size_t)k * 4096 * 512);
      w0 += pp.x; w1 += pp.y;
    }
    ph2 = make_float2(w0, w1);
  }
  __syncthreads();                         // B(0) drained + A(0) visible

  f32x4 acc[4][4] = {};
  const int wo = wave * 64;                // consumer o-range (waves 0-3)
  int cur = 0;
  for (int s = 0; s < nst; ++s) {
    const int nxt = cur ^ 1;
    if (wave >= 4) {
      if (s + 1 < nst) {
        bsrc += 128;
        unsigned char* bn = smem + 16384 + nxt * 32768 + (wave - 4) * 1024;
        #pragma unroll
        for (int p = 0; p < 8; ++p)
          async_cp16(bsrc + (size_t)p * 32 * 8192, bn + p * 4096);
        basis8(ph2.x, pkA); basis8(ph2.y, pkB);
        unsigned char* an = smem + nxt * 8192;
        *(uint4*)&an[am * K3_LDB + acol0] = *(uint4*)&pkA[0];
        *(uint4*)&an[am * K3_LDB + acol1] = *(uint4*)&pkB[0];
        if (s + 2 < nst) {
          psrc += 8;
          float w0 = inval(bias2, i0 + (s + 2) * 8 + il, isf);
          float w1 = inval(bias2, i0 + (s + 2) * 8 + il + 1, isf);
          for (int k = 0; k < kzT2; ++k) {
            float2 pp = *(const float2*)(psrc + (size_t)k * 4096 * 512);
            w0 += pp.x; w1 += pp.y;
          }
          ph2 = make_float2(w0, w1);
        }
      }
    } else {
      const unsigned char* ac = smem + cur * 8192;
      const unsigned char* bc = smem + 16384 + cur * 32768;
      __builtin_amdgcn_s_setprio(1);
      #pragma unroll
      for (int kk = 0; kk < 128; kk += 32) {
        const int cb = (kk + quad * 8) ^ csw;
        i64 bfr[4], afr[4];
        #pragma unroll
        for (int fo = 0; fo < 4; ++fo)
          bfr[fo] = *(const i64*)&bc[(wo + fo * 16 + l16) * K3_LDB + cb];
        #pragma unroll
        for (int fm = 0; fm < 4; ++fm)
          afr[fm] = *(const i64*)&ac[(fm * 16 + l16) * K3_LDB + cb];
        #pragma unroll
        for (int fm = 0; fm < 4; ++fm)
        #pragma unroll
        for (int fo = 0; fo < 4; ++fo)
          acc[fm][fo] = __builtin_amdgcn_mfma_f32_16x16x32_fp8_fp8(afr[fm], bfr[fo], acc[fm][fo], 0, 0, 0);
      }
      __builtin_amdgcn_s_setprio(0);
    }
    __syncthreads();                       // drains B(s+1) async + A(s+1) writes
    cur = nxt;
  }
  if (wave < 4) {
    float* Qk = (float*)(wsbase + QOF(kz));
    #pragma unroll
    for (int fm = 0; fm < 4; ++fm)
    #pragma unroll
    for (int fo = 0; fo < 4; ++fo) {
      int o = wo + fo * 16 + l16;
      #pragma unroll
      for (int r = 0; r < 4; ++r) {
        int n = n0 + fm * 16 + quad * 4 + r;
        Qk[(size_t)n * 256 + o] = acc[fm][fo][r] * INV_SCALE;
      }
    }
  }

  // ---- fused last-block-per-slab reduce + softmax (release/acquire) ----
  __threadfence();                         // release: partial stores visible
  __syncthreads();                         // all threads of block fenced
  int* slast = (int*)smem;                 // alias dead LDS (no extra budget)
  if (t == 0) *slast = (atomicAdd(&cnt[blockIdx.x], 1) == 7) ? 1 : 0;
  __syncthreads();
  if (!*slast) return;
  __threadfence();                         // acquire: see the other 7 planes
  {
    const int rbase = wave * 8;            // 8 rows per wave
    for (int j = 0; j < 8; ++j) {
      const int row = n0 + rbase + j;
      const size_t base = (size_t)row * 256 + lane * 4;
      float v0 = 0.f, v1 = 0.f, v2 = 0.f, v3 = 0.f;
      #pragma unroll
      for (int k = 0; k < 8; ++k) {
        float4 a = *(const float4*)((const float*)(wsbase + QOF(k)) + base);
        v0 += a.x; v1 += a.y; v2 += a.z; v3 += a.w;
      }
      const int o = lane * 4;
      v0 += inval(bias3, o + 0, isf);
      v1 += inval(bias3, o + 1, isf);
      v2 += inval(bias3, o + 2, isf);
      v3 += inval(bias3, o + 3, isf);
      float m = fmaxf(fmaxf(v0, v1), fmaxf(v2, v3));
      #pragma unroll
      for (int off = 32; off; off >>= 1) m = fmaxf(m, __shfl_xor(m, off));
      float e0 = __expf(v0 - m), e1 = __expf(v1 - m), e2 = __expf(v2 - m), e3 = __expf(v3 - m);
      float s = e0 + e1 + e2 + e3;
      #pragma unroll
      for (int off = 32; off; off >>= 1) s += __shfl_xor(s, off);
      float inv = 1.f / s;
      *(float4*)(out + base) = make_float4(e0 * inv, e1 * inv, e2 * inv, e3 * inv);
    }
  }
}

// ---------------------------------------------------------------------------
extern "C" void kernel_launch(void* const* d_in, const int* in_sizes, int n_in,
                              void* d_out, int out_size, void* d_ws, size_t ws_size,
                              hipStream_t stream)
{
  const void* x     = d_in[0];
  const void* W1    = d_in[1];
  const void* b1    = d_in[2];
  const void* gamma = d_in[3];
  const void* beta  = d_in[4];
  const void* c2    = d_in[5];
  const void* bias2 = d_in[6];
  const void* c3    = d_in[7];
  const void* bias3 = d_in[8];

  const int kz2 = 4;   // kan2 K-split: grid (64,2,4)=512 = exactly 2 blocks/CU

  char* ws = (char*)d_ws;
  float*          H    = (float*)(ws + 0);
  unsigned char*  W2F8 = (unsigned char*)(ws + (16ull << 20));
  unsigned char*  W3F8 = (unsigned char*)(ws + (24ull << 20));
  u16*            Xs   = (u16*)(ws + (26ull << 20));
  u16*            W1s  = (u16*)(ws + (33ull << 20));
  float*          P2   = (float*)(ws + (34ull << 20));
  size_t tail = (34ull << 20) + (size_t)kz2 * (8ull << 20) + 524288;
  float2* PT   = (float2*)(ws + tail);
  int*    FLAG = (int*)   (ws + tail + 65536);
  int*    CNT  = (int*)   (ws + tail + 131072);

  prep_all_kernel<<<dim3(2688), dim3(256), 0, stream>>>(x, W1, Xs, W1s, c2, W2F8, c3, W3F8, FLAG, CNT);
  l1_kernel   <<<dim3(64, 8), dim3(256), 0, stream>>>(Xs, W1s, b1, FLAG, H, PT);
  kan2_kernel <<<dim3(64, 2, kz2), dim3(512), 0, stream>>>(H, W2F8, gamma, beta, FLAG, PT, P2, kz2);
  kan3_kernel <<<dim3(64, 1, 8), dim3(512), 0, stream>>>(P2, bias2, W3F8, FLAG, ws, kz2, bias3, (float*)d_out, CNT);
}

// Round 11
// 193.357 us; speedup vs baseline: 1.7117x; 1.7117x over previous
//
#include <hip/hip_runtime.h>
#include <hip/hip_fp16.h>
#include <stdint.h>

typedef unsigned short u16;
typedef unsigned int u32;
typedef long i64;
typedef short bf16x8 __attribute__((ext_vector_type(8)));
typedef float f32x4 __attribute__((ext_vector_type(4)));

#define SCALE_C   1024.f
#define INV_SCALE 0.0009765625f

__device__ __forceinline__ float bf2f(u16 v) { return __uint_as_float(((u32)v) << 16); }

__device__ __forceinline__ u16 f2bf(float a) {
  u32 u = __float_as_uint(a); u += 0x7FFFu + ((u >> 16) & 1u); return (u16)(u >> 16);
}

__device__ __forceinline__ u32 packbf2(float a, float b) {
  u32 ua = __float_as_uint(a); ua += 0x7FFFu + ((ua >> 16) & 1u);
  u32 ub = __float_as_uint(b); ub += 0x7FFFu + ((ub >> 16) & 1u);
  return (ua >> 16) | (ub & 0xFFFF0000u);
}

// 4 floats -> 4 fp8 e4m3 in one dword (2x v_cvt_pk_fp8_f32)
__device__ __forceinline__ u32 packfp8x4(float a, float b, float c, float d) {
  u32 lo = (u32)__builtin_amdgcn_cvt_pk_fp8_f32(a, b, 0, false);
  return (u32)__builtin_amdgcn_cvt_pk_fp8_f32(c, d, (int)lo, true);
}

__device__ __forceinline__ float inval(const void* p, int idx, int isf) {
  return isf ? ((const float*)p)[idx] : bf2f(((const u16*)p)[idx]);
}

// async global->LDS, 16 B per lane, zero VGPR cost. LDS dest must be
// wave-uniform base (HW writes base + lane*16); global src is per-lane.
__device__ __forceinline__ void async_cp16(const void* g, void* l) {
  __builtin_amdgcn_global_load_lds(
      (const __attribute__((address_space(1))) void*)g,
      (__attribute__((address_space(3))) void*)l, 16, 0, 0);
}

// 16-term Chebyshev cos/sin basis -> 8 packed fp8 dwords (x1024 scale in W).
__device__ __forceinline__ void basis16(float a, u32* pk) {
  float s1, c1; __sincosf(a, &s1, &c1);
  float t2 = c1 + c1;
  float cg[16], sg[16];
  cg[0] = c1; sg[0] = s1;
  cg[1] = fmaf(t2, c1, -1.f); sg[1] = t2 * s1;
  #pragma unroll
  for (int g = 2; g < 16; ++g) {
    cg[g] = fmaf(t2, cg[g-1], -cg[g-2]);
    sg[g] = fmaf(t2, sg[g-1], -sg[g-2]);
  }
  #pragma unroll
  for (int j = 0; j < 4; ++j) pk[j]   = packfp8x4(cg[4*j], cg[4*j+1], cg[4*j+2], cg[4*j+3]);
  #pragma unroll
  for (int j = 0; j < 4; ++j) pk[4+j] = packfp8x4(sg[4*j], sg[4*j+1], sg[4*j+2], sg[4*j+3]);
}

// 8-term basis -> 4 packed fp8 dwords (cos x2, sin x2).
__device__ __forceinline__ void basis8(float a, u32* pk) {
  float s1, c1; __sincosf(a, &s1, &c1);
  float t2 = c1 + c1;
  float cg[8], sg[8];
  cg[0] = c1; sg[0] = s1;
  cg[1] = fmaf(t2, c1, -1.f); sg[1] = t2 * s1;
  #pragma unroll
  for (int g = 2; g < 8; ++g) {
    cg[g] = fmaf(t2, cg[g-1], -cg[g-2]);
    sg[g] = fmaf(t2, sg[g-1], -sg[g-2]);
  }
  pk[0] = packfp8x4(cg[0], cg[1], cg[2], cg[3]);
  pk[1] = packfp8x4(cg[4], cg[5], cg[6], cg[7]);
  pk[2] = packfp8x4(sg[0], sg[1], sg[2], sg[3]);
  pk[3] = packfp8x4(sg[4], sg[5], sg[6], sg[7]);
}

// Q3 partial-plane byte offsets within workspace: regions dead by kan3-time
// (H 0-16M, W2F8 16-24M, Xs 26-33M, W1s 33-34M). W3F8 (24-26M) and P2
// (34-66M) are live during kan3 and are avoided.
#define QOF(k) ((size_t)((k) < 6 ? (k) * 4 : 26 + ((k) - 6) * 4) << 20)

// ---------------------------------------------------------------------------
// prep_all: detect dtype + split(x,W1) to bf16-split + coeffs -> fp8 (x1024).
// (r4/r7 form)
// ---------------------------------------------------------------------------
__device__ __forceinline__ void split_body(
    const void* __restrict__ src, u16* __restrict__ dst, int i, int isf, int lo_pos)
{
  int row = i >> 6, g = i & 63;
  float v[4];
  if (isf) {
    float4 t = ((const float4*)src)[i];
    v[0] = t.x; v[1] = t.y; v[2] = t.z; v[3] = t.w;
  } else {
    uint2 t = ((const uint2*)src)[i];
    const u16* p = (const u16*)&t;
    v[0] = bf2f(p[0]); v[1] = bf2f(p[1]); v[2] = bf2f(p[2]); v[3] = bf2f(p[3]);
  }
  u16 hi[4]; float lo[4];
  #pragma unroll
  for (int j = 0; j < 4; ++j) { hi[j] = f2bf(v[j]); lo[j] = v[j] - bf2f(hi[j]); }
  u32 hw0 = (u32)hi[0] | ((u32)hi[1] << 16);
  u32 hw1 = (u32)hi[2] | ((u32)hi[3] << 16);
  u32 lw0 = packbf2(lo[0], lo[1]);
  u32 lw1 = packbf2(lo[2], lo[3]);
  u32* base = (u32*)(dst + (size_t)row * 768);
  int c = g * 2;
  base[c] = hw0; base[c + 1] = hw1;
  if (lo_pos == 1) {
    base[128 + c] = lw0; base[128 + c + 1] = lw1;
    base[256 + c] = hw0; base[256 + c + 1] = hw1;
  } else {
    base[128 + c] = hw0; base[128 + c + 1] = hw1;
    base[256 + c] = lw0; base[256 + c + 1] = lw1;
  }
}

__global__ __launch_bounds__(256) void prep_all_kernel(
    const void* __restrict__ x, const void* __restrict__ W1,
    u16* __restrict__ Xs, u16* __restrict__ W1s,
    const void* __restrict__ c2, unsigned char* __restrict__ w2f8,
    const void* __restrict__ c3, unsigned char* __restrict__ w3f8,
    int* __restrict__ flag)
{
  __shared__ int sf[4];
  const int t = threadIdx.x, wave = t >> 6;
  {
    float v = fabsf(bf2f(((const u16*)W1)[t & 127]));
    int bad = !(v < 1e6f);
    unsigned long long b = __ballot(bad);
    if ((t & 63) == 0) sf[wave] = (b != 0ull) ? 1 : 0;
  }
  __syncthreads();
  const int isf = sf[0] | sf[1] | sf[2] | sf[3];
  const int bid = blockIdx.x;
  if (bid == 0 && t == 0) *flag = isf;
  if (bid < 1024) {
    split_body(x, Xs, bid * 256 + t, isf, 1);
  } else if (bid < 1152) {
    split_body(W1, W1s, (bid - 1024) * 256 + t, isf, 2);
  } else if (bid < 2176) {
    int u = (bid - 1152) * 256 + t;           // 512*512 (o,i)
    int o = u >> 9, i = u & 511;
    u32* d = (u32*)(w2f8 + (size_t)o * 16384 + i * 32);
    if (isf) {
      const float4* f0 = (const float4*)((const float*)c2 + ((size_t)o * 512 + i) * 16);
      const float4* f1 = (const float4*)((const float*)c2 + (size_t)512 * 512 * 16 + ((size_t)o * 512 + i) * 16);
      #pragma unroll
      for (int j = 0; j < 4; ++j) { float4 v = f0[j]; d[j]   = packfp8x4(v.x*SCALE_C, v.y*SCALE_C, v.z*SCALE_C, v.w*SCALE_C); }
      #pragma unroll
      for (int j = 0; j < 4; ++j) { float4 v = f1[j]; d[4+j] = packfp8x4(v.x*SCALE_C, v.y*SCALE_C, v.z*SCALE_C, v.w*SCALE_C); }
    } else {
      const u16* s0 = (const u16*)c2 + ((size_t)o * 512 + i) * 16;
      const u16* s1 = (const u16*)c2 + (size_t)512 * 512 * 16 + ((size_t)o * 512 + i) * 16;
      #pragma unroll
      for (int j = 0; j < 4; ++j) d[j]   = packfp8x4(bf2f(s0[4*j])*SCALE_C, bf2f(s0[4*j+1])*SCALE_C, bf2f(s0[4*j+2])*SCALE_C, bf2f(s0[4*j+3])*SCALE_C);
      #pragma unroll
      for (int j = 0; j < 4; ++j) d[4+j] = packfp8x4(bf2f(s1[4*j])*SCALE_C, bf2f(s1[4*j+1])*SCALE_C, bf2f(s1[4*j+2])*SCALE_C, bf2f(s1[4*j+3])*SCALE_C);
    }
  } else {
    int u = (bid - 2176) * 256 + t;           // 256*512 (o,i)
    int o = u >> 9, i = u & 511;
    u32* d = (u32*)(w3f8 + (size_t)o * 8192 + i * 16);
    if (isf) {
      const float4* f0 = (const float4*)((const float*)c3 + ((size_t)o * 512 + i) * 8);
      const float4* f1 = (const float4*)((const float*)c3 + (size_t)256 * 512 * 8 + ((size_t)o * 512 + i) * 8);
      #pragma unroll
      for (int j = 0; j < 2; ++j) { float4 v = f0[j]; d[j]   = packfp8x4(v.x*SCALE_C, v.y*SCALE_C, v.z*SCALE_C, v.w*SCALE_C); }
      #pragma unroll
      for (int j = 0; j < 2; ++j) { float4 v = f1[j]; d[2+j] = packfp8x4(v.x*SCALE_C, v.y*SCALE_C, v.z*SCALE_C, v.w*SCALE_C); }
    } else {
      const u16* s0 = (const u16*)c3 + ((size_t)o * 512 + i) * 8;
      const u16* s1 = (const u16*)c3 + (size_t)256 * 512 * 8 + ((size_t)o * 512 + i) * 8;
      #pragma unroll
      for (int j = 0; j < 2; ++j) d[j]   = packfp8x4(bf2f(s0[4*j])*SCALE_C, bf2f(s0[4*j+1])*SCALE_C, bf2f(s0[4*j+2])*SCALE_C, bf2f(s0[4*j+3])*SCALE_C);
      #pragma unroll
      for (int j = 0; j < 2; ++j) d[2+j] = packfp8x4(bf2f(s1[4*j])*SCALE_C, bf2f(s1[4*j+1])*SCALE_C, bf2f(s1[4*j+2])*SCALE_C, bf2f(s1[4*j+3])*SCALE_C);
    }
  }
}

// ---------------------------------------------------------------------------
// Kernel 1: h = x @ W1^T + b1 via split-bf16 (K=768), fp32 out + sum/sumsq.
// r11: kan2-proven staging ported — async global_load_lds (zero VGPR),
// linear LDS [64][128] bf16 + XOR byte-swizzle (col ^ ((row&7)<<4), same
// involution on pre-swizzled global source and reads; reads land 2
// lanes/bank = free). Double-buffered (2x32KB = 64KB -> 2 blocks/CU =
// grid 512), ONE barrier per K-step; async(s+1) issues before MFMA(s) so
// the 16-MFMA block covers the load latency. 6 steps of fully-exposed
// latency in the old form -> hidden.
// ---------------------------------------------------------------------------
__global__ __launch_bounds__(256) void l1_kernel(
    const u16* __restrict__ xs, const u16* __restrict__ w1s, const void* __restrict__ b1,
    const int* __restrict__ flag, float* __restrict__ H, float2* __restrict__ PT)
{
  // buf k at smem + k*32768: A [0,16K), B [16K,32K)
  __shared__ __attribute__((aligned(16))) unsigned char smem[65536];
  __shared__ float redbuf[8];
  const int n0 = blockIdx.x * 64, o0 = blockIdx.y * 64;
  const int t = threadIdx.x, wave = t >> 6, lane = t & 63, quad = lane >> 4, l16 = lane & 15;
  const int isf = *flag;
  const int srow = lane >> 4;              // row-within-issue 0..3
  const int scol = (lane & 15) * 16;       // byte col 0..240
  f32x4 acc[4] = {};
  // prologue: async stage ks=0 into buf0 (A: 4 issues/wave, B: 4 issues/wave)
  #pragma unroll
  for (int p = 0; p < 4; ++p) {
    int row = (wave * 4 + p) * 4 + srow;
    int sb = scol ^ ((row & 7) << 4);      // pre-swizzled source byte col
    async_cp16(xs  + (size_t)(n0 + row) * 768 + (sb >> 1),
               smem + (wave * 4 + p) * 1024);
    async_cp16(w1s + (size_t)(o0 + row) * 768 + (sb >> 1),
               smem + 16384 + (wave * 4 + p) * 1024);
  }
  int cur = 0;
  for (int s = 0; s < 6; ++s) {
    __syncthreads();                       // drains async writes of buf[cur]
    if (s + 1 < 6) {                       // issue next step into idle buffer
      const int ksn = (s + 1) * 128;
      unsigned char* bufn = smem + (cur ^ 1) * 32768;
      #pragma unroll
      for (int p = 0; p < 4; ++p) {
        int row = (wave * 4 + p) * 4 + srow;
        int sb = scol ^ ((row & 7) << 4);
        async_cp16(xs  + (size_t)(n0 + row) * 768 + ksn + (sb >> 1),
                   bufn + (wave * 4 + p) * 1024);
        async_cp16(w1s + (size_t)(o0 + row) * 768 + ksn + (sb >> 1),
                   bufn + 16384 + (wave * 4 + p) * 1024);
      }
    }
    const unsigned char* ba = smem + cur * 32768;
    const unsigned char* bb = ba + 16384;
    #pragma unroll
    for (int kk = 0; kk < 128; kk += 32) {
      const int cb = (kk * 2 + quad * 16) ^ ((l16 & 7) << 4);
      bf16x8 av = *(const bf16x8*)&ba[(wave * 16 + l16) * 256 + cb];
      #pragma unroll
      for (int fo = 0; fo < 4; ++fo) {
        bf16x8 bv = *(const bf16x8*)&bb[(fo * 16 + l16) * 256 + cb];
        acc[fo] = __builtin_amdgcn_mfma_f32_16x16x32_bf16(av, bv, acc[fo], 0, 0, 0);
      }
    }
    cur ^= 1;
  }
  float s = 0.f, sq = 0.f;
  #pragma unroll
  for (int fo = 0; fo < 4; ++fo) {
    int o = o0 + fo * 16 + l16;
    float bias = inval(b1, o, isf);
    #pragma unroll
    for (int r = 0; r < 4; ++r) {
      int n = n0 + wave * 16 + quad * 4 + r;
      float h = acc[fo][r] + bias;
      H[(size_t)n * 512 + o] = h;
      s += h; sq += h * h;
    }
  }
  #pragma unroll
  for (int off = 32; off; off >>= 1) { s += __shfl_down(s, off); sq += __shfl_down(sq, off); }
  if (lane == 0) { redbuf[wave] = s; redbuf[4 + wave] = sq; }
  __syncthreads();
  if (t == 0) {
    float S = redbuf[0] + redbuf[1] + redbuf[2] + redbuf[3];
    float Q = redbuf[4] + redbuf[5] + redbuf[6] + redbuf[7];
    PT[blockIdx.y * 64 + blockIdx.x] = make_float2(S, Q);
  }
}

// ---------------------------------------------------------------------------
// Kernel 3: BN+ReLU+basis + FP8 MFMA GEMM — producer/consumer wave split
// (r4/r7 form, best measured 60.9us). Plane-partial P2 output (kz=4).
// ---------------------------------------------------------------------------
#define K2_LDB 128
__global__ __launch_bounds__(512, 4) void kan2_kernel(
    const float* __restrict__ H, const unsigned char* __restrict__ w2f8,
    const void* __restrict__ gammap, const void* __restrict__ betap,
    const int* __restrict__ flag, const float2* __restrict__ PT,
    float* __restrict__ P, int kzT)
{
  __shared__ __attribute__((aligned(16))) unsigned char smem[81920];
  // layout: A0[0,8K) A1[8K,16K) B0[16K,48K) B1[48K,80K); sred in B1 tail
  float* sred = (float*)(smem + 81888);
  const int n0 = blockIdx.x * 64, o0 = blockIdx.y * 256, kz = blockIdx.z;
  const int t = threadIdx.x, wave = t >> 6, lane = t & 63, quad = lane >> 4, l16 = lane & 15;
  const int nst = 128 / kzT;               // 32 for kzT=4
  const int i0 = kz * nst * 4;
  const int csw = (l16 & 7) << 4;
  const int isf = *flag;

  // producer-side state
  const int pt = t - 256;
  const int am = pt >> 2, ai = pt & 3;     // 64 rows x 4 i
  const int r0 = pt >> 3, seg = pt & 7;    // B staging map
  const unsigned char* bsrc = w2f8 + (size_t)(o0 + (r0 & 63)) * 16384 + (size_t)i0 * 32
                              + (((seg & 7) * 16) ^ ((r0 & 7) << 4));
  const float* hsrc = H + (size_t)(n0 + (am & 63)) * 512 + i0 + (ai & 3);
  const int acol0 = ((ai & 3) * 32) ^ ((am & 7) << 4);
  const int acol1 = ((ai & 3) * 32 + 16) ^ ((am & 7) << 4);
  float mean = 0.f, gs = 0.f, beta = 0.f, ph = 0.f;
  u32 pk[8];

  if (wave >= 4) {
    // issue B(0) async into B0 (drains at barrier 1)
    unsigned char* b0 = smem + 16384 + (wave - 4) * 1024;
    #pragma unroll
    for (int p = 0; p < 8; ++p)
      async_cp16(bsrc + (size_t)p * 32 * 16384, b0 + p * 4096);
    // stats partial reduce
    float2 pa = PT[pt], pb = PT[pt + 256];
    float ss = pa.x + pb.x, qs = pa.y + pb.y;
    #pragma unroll
    for (int off = 32; off; off >>= 1) { ss += __shfl_down(ss, off); qs += __shfl_down(qs, off); }
    if (lane == 0) { sred[(wave - 4) * 2] = ss; sred[(wave - 4) * 2 + 1] = qs; }
  }
  __syncthreads();                         // sred visible; B(0) drained
  if (wave >= 4) {
    const float Ssum = sred[0] + sred[2] + sred[4] + sred[6];
    const float Qsum = sred[1] + sred[3] + sred[5] + sred[7];
    const float Nn = 4096.f * 512.f;
    mean = Ssum / Nn;
    const float rstd = rsqrtf(Qsum / Nn - mean * mean + 1e-5f);
    gs = inval(gammap, 0, isf) * rstd;
    beta = inval(betap, 0, isf);
    // A(0): trig for step 0
    float a = fmaxf((*hsrc - mean) * gs + beta, 0.f);
    hsrc += 4;
    basis16(a, pk);
    *(uint4*)&smem[am * K2_LDB + acol0] = *(uint4*)&pk[0];
    *(uint4*)&smem[am * K2_LDB + acol1] = *(uint4*)&pk[4];
    if (nst > 1) { ph = *hsrc; hsrc += 4; }
  }
  __syncthreads();                         // A(0) visible

  f32x4 acc[2][8] = {};
  const int wm = (wave & 1) * 32, wo = (wave >> 1) * 128;  // consumer tile
  int cur = 0;
  for (int s = 0; s < nst; ++s) {
    const int nxt = cur ^ 1;
    if (wave >= 4) {
      if (s + 1 < nst) {
        bsrc += 128;
        unsigned char* bn = smem + 16384 + nxt * 32768 + (wave - 4) * 1024;
        #pragma unroll
        for (int p = 0; p < 8; ++p)
          async_cp16(bsrc + (size_t)p * 32 * 16384, bn + p * 4096);
        float a = fmaxf((ph - mean) * gs + beta, 0.f);
        basis16(a, pk);
        unsigned char* an = smem + nxt * 8192;
        *(uint4*)&an[am * K2_LDB + acol0] = *(uint4*)&pk[0];
        *(uint4*)&an[am * K2_LDB + acol1] = *(uint4*)&pk[4];
        if (s + 2 < nst) { ph = *hsrc; hsrc += 4; }
      }
    } else {
      const unsigned char* ac = smem + cur * 8192;
      const unsigned char* bc = smem + 16384 + cur * 32768;
      #pragma unroll
      for (int kk = 0; kk < 128; kk += 32) {
        const int cb = (kk + quad * 8) ^ csw;
        i64 bfr[8], afr[2];
        #pragma unroll
        for (int fo = 0; fo < 8; ++fo)
          bfr[fo] = *(const i64*)&bc[(wo + fo * 16 + l16) * K2_LDB + cb];
        #pragma unroll
        for (int fm = 0; fm < 2; ++fm)
          afr[fm] = *(const i64*)&ac[(wm + fm * 16 + l16) * K2_LDB + cb];
        #pragma unroll
        for (int fm = 0; fm < 2; ++fm)
        #pragma unroll
        for (int fo = 0; fo < 8; ++fo)
          acc[fm][fo] = __builtin_amdgcn_mfma_f32_16x16x32_fp8_fp8(afr[fm], bfr[fo], acc[fm][fo], 0, 0, 0);
      }
    }
    __syncthreads();                       // drains B(s+1) async + A(s+1) writes
    cur = nxt;
  }
  if (wave < 4) {
    float* Pk = P + (size_t)kz * (4096 * 512);
    #pragma unroll
    for (int fm = 0; fm < 2; ++fm)
    #pragma unroll
    for (int fo = 0; fo < 8; ++fo) {
      int o = o0 + wo + fo * 16 + l16;
      #pragma unroll
      for (int r = 0; r < 4; ++r) {
        int n = n0 + wm + fm * 16 + quad * 4 + r;
        Pk[(size_t)n * 512 + o] = acc[fm][fo][r] * INV_SCALE;
      }
    }
  }
}

// ---------------------------------------------------------------------------
// Kernel 4: basis (grid=8) + FP8 MFMA GEMM — producer/consumer wave split
// (r7 form). Q3 planes land in dead workspace regions via QOF table.
// ---------------------------------------------------------------------------
#define K3_LDB 128
__global__ __launch_bounds__(512, 4) void kan3_kernel(
    const float* __restrict__ P2, const void* __restrict__ bias2,
    const unsigned char* __restrict__ w3f8,
    const int* __restrict__ flag, char* __restrict__ wsbase, int kzT2)
{
  // layout: A0[0,8K) A1[8K,16K) B0[16K,48K) B1[48K,80K)
  __shared__ __attribute__((aligned(16))) unsigned char smem[81920];
  const int n0 = blockIdx.x * 64, kz = blockIdx.z;
  const int t = threadIdx.x, wave = t >> 6, lane = t & 63, quad = lane >> 4, l16 = lane & 15;
  const int i0 = kz * 64;                  // 64 i per block, 8 steps x 8 i
  const int nst = 8;
  const int csw = (l16 & 7) << 4;
  const int isf = *flag;

  // producer-side state
  const int pt = t - 256;
  const int am = (pt >> 2) & 63;           // producer n-row 0..63
  const int il = (pt & 3) * 2;             // i-pair base within step
  const int r0 = (pt >> 3) & 31, seg = pt & 7;
  const unsigned char* bsrc = w3f8 + (size_t)r0 * 8192 + (size_t)i0 * 16
                              + ((seg * 16) ^ ((r0 & 7) << 4));
  const float* psrc = P2 + (size_t)(n0 + am) * 512 + i0 + il;
  const int acol0 = (il * 16) ^ ((am & 7) << 4);
  const int acol1 = ((il + 1) * 16) ^ ((am & 7) << 4);
  float2 ph2 = make_float2(0.f, 0.f);
  u32 pkA[4], pkB[4];

  if (wave >= 4) {
    // B(0) async into B0
    unsigned char* b0 = smem + 16384 + (wave - 4) * 1024;
    #pragma unroll
    for (int p = 0; p < 8; ++p)
      async_cp16(bsrc + (size_t)p * 32 * 8192, b0 + p * 4096);
    // ph for step 0: bias2 + sum of kzT2 P2 planes
    float v0 = inval(bias2, i0 + il, isf);
    float v1 = inval(bias2, i0 + il + 1, isf);
    for (int k = 0; k < kzT2; ++k) {
      float2 pp = *(const float2*)(psrc + (size_t)k * 4096 * 512);
      v0 += pp.x; v1 += pp.y;
    }
    // A(0)
    basis8(v0, pkA); basis8(v1, pkB);
    *(uint4*)&smem[am * K3_LDB + acol0] = *(uint4*)&pkA[0];
    *(uint4*)&smem[am * K3_LDB + acol1] = *(uint4*)&pkB[0];
    // prefetch ph for step 1
    psrc += 8;
    float w0 = inval(bias2, i0 + 8 + il, isf);
    float w1 = inval(bias2, i0 + 8 + il + 1, isf);
    for (int k = 0; k < kzT2; ++k) {
      float2 pp = *(const float2*)(psrc + (size_t)k * 4096 * 512);
      w0 += pp.x; w1 += pp.y;
    }
    ph2 = make_float2(w0, w1);
  }
  __syncthreads();                         // B(0) drained + A(0) visible

  f32x4 acc[4][4] = {};
  const int wo = wave * 64;                // consumer o-range (waves 0-3)
  int cur = 0;
  for (int s = 0; s < nst; ++s) {
    const int nxt = cur ^ 1;
    if (wave >= 4) {
      if (s + 1 < nst) {
        bsrc += 128;
        unsigned char* bn = smem + 16384 + nxt * 32768 + (wave - 4) * 1024;
        #pragma unroll
        for (int p = 0; p < 8; ++p)
          async_cp16(bsrc + (size_t)p * 32 * 8192, bn + p * 4096);
        basis8(ph2.x, pkA); basis8(ph2.y, pkB);
        unsigned char* an = smem + nxt * 8192;
        *(uint4*)&an[am * K3_LDB + acol0] = *(uint4*)&pkA[0];
        *(uint4*)&an[am * K3_LDB + acol1] = *(uint4*)&pkB[0];
        if (s + 2 < nst) {
          psrc += 8;
          float w0 = inval(bias2, i0 + (s + 2) * 8 + il, isf);
          float w1 = inval(bias2, i0 + (s + 2) * 8 + il + 1, isf);
          for (int k = 0; k < kzT2; ++k) {
            float2 pp = *(const float2*)(psrc + (size_t)k * 4096 * 512);
            w0 += pp.x; w1 += pp.y;
          }
          ph2 = make_float2(w0, w1);
        }
      }
    } else {
      const unsigned char* ac = smem + cur * 8192;
      const unsigned char* bc = smem + 16384 + cur * 32768;
      __builtin_amdgcn_s_setprio(1);
      #pragma unroll
      for (int kk = 0; kk < 128; kk += 32) {
        const int cb = (kk + quad * 8) ^ csw;
        i64 bfr[4], afr[4];
        #pragma unroll
        for (int fo = 0; fo < 4; ++fo)
          bfr[fo] = *(const i64*)&bc[(wo + fo * 16 + l16) * K3_LDB + cb];
        #pragma unroll
        for (int fm = 0; fm < 4; ++fm)
          afr[fm] = *(const i64*)&ac[(fm * 16 + l16) * K3_LDB + cb];
        #pragma unroll
        for (int fm = 0; fm < 4; ++fm)
        #pragma unroll
        for (int fo = 0; fo < 4; ++fo)
          acc[fm][fo] = __builtin_amdgcn_mfma_f32_16x16x32_fp8_fp8(afr[fm], bfr[fo], acc[fm][fo], 0, 0, 0);
      }
      __builtin_amdgcn_s_setprio(0);
    }
    __syncthreads();                       // drains B(s+1) async + A(s+1) writes
    cur = nxt;
  }
  if (wave < 4) {
    float* Qk = (float*)(wsbase + QOF(kz));
    #pragma unroll
    for (int fm = 0; fm < 4; ++fm)
    #pragma unroll
    for (int fo = 0; fo < 4; ++fo) {
      int o = wo + fo * 16 + l16;
      #pragma unroll
      for (int r = 0; r < 4; ++r) {
        int n = n0 + fm * 16 + quad * 4 + r;
        Qk[(size_t)n * 256 + o] = acc[fm][fo][r] * INV_SCALE;
      }
    }
  }
}

// ---------------------------------------------------------------------------
// Kernel 5: fused 8-partial reduce + bias3 + row softmax + fp32 store.
// ---------------------------------------------------------------------------
__global__ __launch_bounds__(256) void softmax_kernel(
    const char* __restrict__ wsbase, const void* __restrict__ bias3,
    const int* __restrict__ flag, float* __restrict__ out)
{
  const int t = threadIdx.x, wave = t >> 6, lane = t & 63;
  const int row = blockIdx.x * 4 + wave;
  const int isf = *flag;
  size_t base = (size_t)row * 256 + lane * 4;
  float v0 = 0.f, v1 = 0.f, v2 = 0.f, v3 = 0.f;
  #pragma unroll
  for (int k = 0; k < 8; ++k) {
    float4 a = *(const float4*)((const float*)(wsbase + QOF(k)) + base);
    v0 += a.x; v1 += a.y; v2 += a.z; v3 += a.w;
  }
  int o = lane * 4;
  v0 += inval(bias3, o + 0, isf);
  v1 += inval(bias3, o + 1, isf);
  v2 += inval(bias3, o + 2, isf);
  v3 += inval(bias3, o + 3, isf);
  float m = fmaxf(fmaxf(v0, v1), fmaxf(v2, v3));
  #pragma unroll
  for (int off = 32; off; off >>= 1) m = fmaxf(m, __shfl_xor(m, off));
  float e0 = __expf(v0 - m), e1 = __expf(v1 - m), e2 = __expf(v2 - m), e3 = __expf(v3 - m);
  float s = e0 + e1 + e2 + e3;
  #pragma unroll
  for (int off = 32; off; off >>= 1) s += __shfl_xor(s, off);
  float inv = 1.f / s;
  *(float4*)(out + base) = make_float4(e0 * inv, e1 * inv, e2 * inv, e3 * inv);
}

// ---------------------------------------------------------------------------
extern "C" void kernel_launch(void* const* d_in, const int* in_sizes, int n_in,
                              void* d_out, int out_size, void* d_ws, size_t ws_size,
                              hipStream_t stream)
{
  const void* x     = d_in[0];
  const void* W1    = d_in[1];
  const void* b1    = d_in[2];
  const void* gamma = d_in[3];
  const void* beta  = d_in[4];
  const void* c2    = d_in[5];
  const void* bias2 = d_in[6];
  const void* c3    = d_in[7];
  const void* bias3 = d_in[8];

  const int kz2 = 4;   // kan2 K-split: grid (64,2,4)=512 = exactly 2 blocks/CU

  char* ws = (char*)d_ws;
  float*          H    = (float*)(ws + 0);
  unsigned char*  W2F8 = (unsigned char*)(ws + (16ull << 20));
  unsigned char*  W3F8 = (unsigned char*)(ws + (24ull << 20));
  u16*            Xs   = (u16*)(ws + (26ull << 20));
  u16*            W1s  = (u16*)(ws + (33ull << 20));
  float*          P2   = (float*)(ws + (34ull << 20));
  size_t tail = (34ull << 20) + (size_t)kz2 * (8ull << 20) + 524288;
  float2* PT   = (float2*)(ws + tail);
  int*    FLAG = (int*)   (ws + tail + 65536);

  prep_all_kernel<<<dim3(2688), dim3(256), 0, stream>>>(x, W1, Xs, W1s, c2, W2F8, c3, W3F8, FLAG);
  l1_kernel   <<<dim3(64, 8), dim3(256), 0, stream>>>(Xs, W1s, b1, FLAG, H, PT);
  kan2_kernel <<<dim3(64, 2, kz2), dim3(512), 0, stream>>>(H, W2F8, gamma, beta, FLAG, PT, P2, kz2);
  kan3_kernel <<<dim3(64, 1, 8), dim3(512), 0, stream>>>(P2, bias2, W3F8, FLAG, ws, kz2);
  softmax_kernel<<<dim3(1024), dim3(256), 0, stream>>>(ws, bias3, FLAG, (float*)d_out);
}